// Round 10
// baseline (681.077 us; speedup 1.0000x reference)
//
#include <hip/hip_runtime.h>

// ---------------- problem constants ----------------
#define MAX_IN   1024
#define MAX_OUT  4096
#define LOW_RANK 64
#define N_ARCH   16
#define HYP_HID  128
#define BATCH_M  8192   // 4 * 2048

typedef __attribute__((ext_vector_type(8))) short short8;   // 8 x bf16
typedef __attribute__((ext_vector_type(4))) float f32x4;

// round-to-nearest-even fp32 -> bf16
__device__ __forceinline__ unsigned short f2bf(float f) {
  union { float f; unsigned int u; } c; c.f = f;
  unsigned int r = c.u + 0x7fffu + ((c.u >> 16) & 1u);
  return (unsigned short)(r >> 16);
}

__device__ __forceinline__ void gload16(const unsigned short* g, unsigned short* l) {
  __builtin_amdgcn_global_load_lds(
      (const __attribute__((address_space(1))) unsigned int*)(g),
      (__attribute__((address_space(3))) unsigned int*)(l), 16, 0, 0);
}

// ---------------- kernel 1: X fp32 -> bf16 ----------------
__global__ __launch_bounds__(256) void convert_x(const float* __restrict__ in,
                                                 unsigned short* __restrict__ out) {
  size_t i = (size_t)blockIdx.x * 256 + threadIdx.x;
  float4 v = *(const float4*)(in + i * 4);
  ushort4 o;
  o.x = f2bf(v.x); o.y = f2bf(v.y); o.z = f2bf(v.z); o.w = f2bf(v.w);
  *(ushort4*)(out + i * 4) = o;
}

// ---------------- kernel 2: fused prep  W = base + (hyp MLP) @ lr ----------------
// (R8-verified: 512 blocks x 256 thr)
__global__ __launch_bounds__(256) void build_w_fused(
    const float* __restrict__ w1, const float* __restrict__ b1,
    const float* __restrict__ e,
    const float* __restrict__ hyp_w2, const float* __restrict__ hyp_b2,
    const float* __restrict__ base_w, const float* __restrict__ lrf,
    unsigned short* __restrict__ Wbf) {
  __shared__ float hs[HYP_HID];
  __shared__ float lefts[8 * LOW_RANK];
  const int tid = threadIdx.x;
  const int o0 = blockIdx.x * 8;

  if (tid < HYP_HID) {
    const float4* wr = (const float4*)(w1 + tid * N_ARCH);
    float s = b1[tid];
#pragma unroll
    for (int c = 0; c < 4; c++) {
      float4 wv = wr[c];
      float4 ev = *(const float4*)(e + c * 4);
      s += wv.x * ev.x + wv.y * ev.y + wv.z * ev.z + wv.w * ev.w;
    }
    hs[tid] = fmaxf(s, 0.0f);
  }
  __syncthreads();

  const int lane = tid & 63;
  const int w = tid >> 6;
  const int g = lane >> 3, gl = lane & 7;
  float4 hf[4];
#pragma unroll
  for (int c = 0; c < 4; c++) hf[c] = *(const float4*)(hs + c * 32 + gl * 4);
#pragma unroll 4
  for (int it = 0; it < 16; ++it) {
    const int rl = w * 128 + it * 8 + g;    // 0..511
    const float* rp = hyp_w2 + (size_t)(o0 * LOW_RANK + rl) * HYP_HID;
    float s = 0.f;
#pragma unroll
    for (int c = 0; c < 4; c++) {
      float4 v = *(const float4*)(rp + c * 32 + gl * 4);
      s += v.x * hf[c].x + v.y * hf[c].y + v.z * hf[c].z + v.w * hf[c].w;
    }
    s += __shfl_xor(s, 4);
    s += __shfl_xor(s, 2);
    s += __shfl_xor(s, 1);
    if (gl == 0) lefts[rl] = s + hyp_b2[o0 * LOW_RANK + rl];
  }
  __syncthreads();

#pragma unroll
  for (int kk = 0; kk < 4; kk++) {
    const int k = kk * 256 + tid;
    float acc[8];
#pragma unroll
    for (int oi = 0; oi < 8; oi++) acc[oi] = base_w[(size_t)(o0 + oi) * MAX_IN + k];
    for (int r = 0; r < LOW_RANK; r++) {
      float lv = lrf[r * MAX_IN + k];
#pragma unroll
      for (int oi = 0; oi < 8; oi++) acc[oi] += lefts[oi * LOW_RANK + r] * lv;
    }
#pragma unroll
    for (int oi = 0; oi < 8; oi++)
      Wbf[(size_t)(o0 + oi) * MAX_IN + k] = f2bf(acc[oi]);
  }
}

// ---------------- kernel 3: GEMM, 2 blocks/CU  C = Xbf @ Wbf^T + bias ----------------
// 256x256 tile, BK=32, NT=32. 8 waves (2M x 4N), wave tile 128x64, 16x16x32 MFMA.
// 2 LDS slots x 32 KB = 64 KB -> 2 blocks/CU co-resident (inter-block overlap
// fills barrier drains, prologue, and the fp32 C-write epilogue).
// Simple rotation: stage(t+1) -> vmcnt(4) -> barrier -> 12 ds_read + 32 MFMA
// (compiler-placed lgkmcnt) -> barrier.
// Swizzle (R6-verified 0-conflict): row = 32 ushorts = 4 x 16B chunks;
// phys chunk j = c ^ ((r>>1)&3); staged via inverse-swizzled GLOBAL source
// + linear gload_lds dest (rule #21).
__global__ __launch_bounds__(512, 4) void gemm_kernel(
    const unsigned short* __restrict__ A,   // [M][K] bf16
    const unsigned short* __restrict__ B,   // [N][K] bf16 (= W)
    const float* __restrict__ bias,         // [N]
    float* __restrict__ C) {                // [M][N] fp32
  constexpr int K = MAX_IN;
  constexpr int N = MAX_OUT;
  constexpr int SLOT = 16384;              // ushorts per slot (A 8192 + B 8192)
  constexpr int BOFF = 8192;
  constexpr int NT = K / 32;               // 32
  __shared__ __align__(16) unsigned short lds[2 * SLOT];  // 64 KB

  const int tid = threadIdx.x;             // 0..511
  const int lane = tid & 63;
  const int w = tid >> 6;                  // wave 0..7
  const int wm = w >> 2, wn = w & 3;       // 2M x 4N
  const int fl = lane & 15, hi = lane >> 4;

  // XCD macro-map (R6-verified, FETCH ~49 MB): xcd gets an 8x8 macro-tile
  const int orig = blockIdx.x;
  const int macro = orig & 7;
  const int mj = orig >> 3;                // 0..63
  const int bm = ((macro >> 1) * 8 + (mj >> 3)) * 256;   // 32 M-tiles
  const int bn = ((macro & 1) * 8 + (mj & 7)) * 256;     // 16 N-tiles

  // staging: thread tid covers row rid = tid>>2 (+128 for 2nd half),
  // phys chunk tid&3; logical chunk cst = (tid&3) ^ ((rid>>1)&3)
  const int rid = tid >> 2;
  const int cst = (tid & 3) ^ ((rid >> 1) & 3);
  const unsigned short* Asrc = A + (size_t)(bm + rid) * K + cst * 8;
  const unsigned short* Bsrc = B + (size_t)(bn + rid) * K + cst * 8;

  // fragment reads: row r, logical chunk hi -> phys chunk hi ^ ((r>>1)&3)
  int aoff[8], boff[4];
#pragma unroll
  for (int m = 0; m < 8; m++) {
    const int r = wm * 128 + m * 16 + fl;
    aoff[m] = r * 32 + ((hi ^ ((r >> 1) & 3)) * 8);
  }
#pragma unroll
  for (int n = 0; n < 4; n++) {
    const int r = wn * 64 + n * 16 + fl;
    boff[n] = BOFF + r * 32 + ((hi ^ ((r >> 1) & 3)) * 8);
  }

  f32x4 acc[8][4];
#pragma unroll
  for (int m = 0; m < 8; m++)
#pragma unroll
    for (int n = 0; n < 4; n++) acc[m][n] = (f32x4){0.f, 0.f, 0.f, 0.f};

#define STAGE(s, kt)                                                    \
  do {                                                                  \
    unsigned short* lb_ = &lds[(s) * SLOT];                             \
    gload16(Asrc + (kt) * 32, &lb_[tid * 8]);                           \
    gload16(Asrc + (size_t)128 * K + (kt) * 32, &lb_[(512 + tid) * 8]); \
    gload16(Bsrc + (kt) * 32, &lb_[BOFF + tid * 8]);                    \
    gload16(Bsrc + (size_t)128 * K + (kt) * 32,                         \
            &lb_[BOFF + (512 + tid) * 8]);                              \
  } while (0)

  STAGE(0, 0);

  for (int t = 0; t < NT; ++t) {
    if (t + 1 < NT) {
      STAGE((t + 1) & 1, t + 1);
      asm volatile("s_waitcnt vmcnt(4)" ::: "memory");  // tile t landed
    } else {
      asm volatile("s_waitcnt vmcnt(0)" ::: "memory");
    }
    __builtin_amdgcn_s_barrier();
    __builtin_amdgcn_sched_barrier(0);

    const unsigned short* lb = &lds[(t & 1) * SLOT];
    short8 a[8], b[4];
#pragma unroll
    for (int m = 0; m < 8; m++) a[m] = *(const short8*)&lb[aoff[m]];
#pragma unroll
    for (int n = 0; n < 4; n++) b[n] = *(const short8*)&lb[boff[n]];
    __builtin_amdgcn_s_setprio(1);
#pragma unroll
    for (int m = 0; m < 8; m++)
#pragma unroll
      for (int n = 0; n < 4; n++)
        acc[m][n] = __builtin_amdgcn_mfma_f32_16x16x32_bf16(a[m], b[n], acc[m][n], 0, 0, 0);
    __builtin_amdgcn_s_setprio(0);
    __builtin_amdgcn_s_barrier();
    __builtin_amdgcn_sched_barrier(0);
  }
#undef STAGE

  // ---- epilogue: C/D layout col=lane&15, row=(lane>>4)*4+j ----
  float bv[4];
#pragma unroll
  for (int n = 0; n < 4; n++) bv[n] = bias[bn + wn * 64 + n * 16 + fl];
#pragma unroll
  for (int m = 0; m < 8; m++) {
    const int gr0 = bm + wm * 128 + m * 16 + hi * 4;
#pragma unroll
    for (int n = 0; n < 4; n++) {
      const int gc = bn + wn * 64 + n * 16 + fl;
#pragma unroll
      for (int jj = 0; jj < 4; jj++)
        C[(size_t)(gr0 + jj) * N + gc] = acc[m][n][jj] + bv[n];
    }
  }
}

// ---------------- launcher ----------------
extern "C" void kernel_launch(void* const* d_in, const int* in_sizes, int n_in,
                              void* d_out, int out_size, void* d_ws, size_t ws_size,
                              hipStream_t stream) {
  const float* x      = (const float*)d_in[0];
  const float* embed  = (const float*)d_in[1];
  const float* base_w = (const float*)d_in[2];
  const float* base_b = (const float*)d_in[3];
  const float* lrf    = (const float*)d_in[4];
  const float* w1     = (const float*)d_in[5];
  const float* b1     = (const float*)d_in[6];
  const float* w2     = (const float*)d_in[7];
  const float* b2     = (const float*)d_in[8];
  float* out = (float*)d_out;

  char* ws = (char*)d_ws;
  unsigned short* Xbf = (unsigned short*)ws;                                   // 16 MB
  unsigned short* Wbf = (unsigned short*)(ws + (size_t)BATCH_M * MAX_IN * 2);  // 8 MB

  hipLaunchKernelGGL(convert_x, dim3(BATCH_M * MAX_IN / 1024), dim3(256), 0, stream, x, Xbf);
  hipLaunchKernelGGL(build_w_fused, dim3(MAX_OUT / 8), dim3(256), 0, stream,
                     w1, b1, embed, w2, b2, base_w, lrf, Wbf);
  hipLaunchKernelGGL(gemm_kernel, dim3((BATCH_M / 256) * (MAX_OUT / 256)), dim3(512), 0, stream,
                     Xbf, Wbf, base_b, out);
}

// Round 11
// 146.649 us; speedup vs baseline: 4.6443x; 4.6443x over previous
//
#include <hip/hip_runtime.h>

// ---------------- problem constants ----------------
#define MAX_IN   1024
#define MAX_OUT  4096
#define LOW_RANK 64
#define N_ARCH   16
#define HYP_HID  128
#define BATCH_M  8192   // 4 * 2048

typedef __attribute__((ext_vector_type(8))) short short8;   // 8 x bf16
typedef __attribute__((ext_vector_type(4))) float f32x4;

// round-to-nearest-even fp32 -> bf16
__device__ __forceinline__ unsigned short f2bf(float f) {
  union { float f; unsigned int u; } c; c.f = f;
  unsigned int r = c.u + 0x7fffu + ((c.u >> 16) & 1u);
  return (unsigned short)(r >> 16);
}

__device__ __forceinline__ void gload16(const unsigned short* g, unsigned short* l) {
  __builtin_amdgcn_global_load_lds(
      (const __attribute__((address_space(1))) unsigned int*)(g),
      (__attribute__((address_space(3))) unsigned int*)(l), 16, 0, 0);
}

// ---------------- kernel 1: fused prep ----------------
// blocks 0..1023:    W rows (4 per block) = base + (hyp MLP) @ lr  -> Wbf
// blocks 1024..3071: X fp32 -> bf16 (4096 floats per block)
__global__ __launch_bounds__(256) void prep_kernel(
    const float* __restrict__ x, unsigned short* __restrict__ Xbf,
    const float* __restrict__ w1, const float* __restrict__ b1,
    const float* __restrict__ e,
    const float* __restrict__ hyp_w2, const float* __restrict__ hyp_b2,
    const float* __restrict__ base_w, const float* __restrict__ lrf,
    unsigned short* __restrict__ Wbf) {
  const int tid = threadIdx.x;
  if (blockIdx.x >= 1024) {
    // ---- convert role ----
    const size_t base = (size_t)(blockIdx.x - 1024) * 4096;
#pragma unroll
    for (int it = 0; it < 4; it++) {
      const size_t i = base + it * 1024 + tid * 4;
      float4 v = *(const float4*)(x + i);
      ushort4 o;
      o.x = f2bf(v.x); o.y = f2bf(v.y); o.z = f2bf(v.z); o.w = f2bf(v.w);
      *(ushort4*)(Xbf + i) = o;
    }
    return;
  }
  // ---- W-build role: 4 output rows per block ----
  __shared__ float hs[HYP_HID];
  __shared__ float lefts[4 * LOW_RANK];
  const int o0 = blockIdx.x * 4;

  if (tid < HYP_HID) {
    const float4* wr = (const float4*)(w1 + tid * N_ARCH);
    float s = b1[tid];
#pragma unroll
    for (int c = 0; c < 4; c++) {
      float4 wv = wr[c];
      float4 ev = *(const float4*)(e + c * 4);
      s += wv.x * ev.x + wv.y * ev.y + wv.z * ev.z + wv.w * ev.w;
    }
    hs[tid] = fmaxf(s, 0.0f);
  }
  __syncthreads();

  const int lane = tid & 63;
  const int w = tid >> 6;
  const int g = lane >> 3, gl = lane & 7;
  float4 hf[4];
#pragma unroll
  for (int c = 0; c < 4; c++) hf[c] = *(const float4*)(hs + c * 32 + gl * 4);
#pragma unroll
  for (int it = 0; it < 8; ++it) {
    const int rl = w * 64 + it * 8 + g;     // 0..255
    const float* rp = hyp_w2 + (size_t)(o0 * LOW_RANK + rl) * HYP_HID;
    float s = 0.f;
#pragma unroll
    for (int c = 0; c < 4; c++) {
      float4 v = *(const float4*)(rp + c * 32 + gl * 4);
      s += v.x * hf[c].x + v.y * hf[c].y + v.z * hf[c].z + v.w * hf[c].w;
    }
    s += __shfl_xor(s, 4);
    s += __shfl_xor(s, 2);
    s += __shfl_xor(s, 1);
    if (gl == 0) lefts[rl] = s + hyp_b2[o0 * LOW_RANK + rl];
  }
  __syncthreads();

#pragma unroll
  for (int kk = 0; kk < 4; kk++) {
    const int k = kk * 256 + tid;
    float acc[4];
#pragma unroll
    for (int oi = 0; oi < 4; oi++) acc[oi] = base_w[(size_t)(o0 + oi) * MAX_IN + k];
    for (int r = 0; r < LOW_RANK; r++) {
      float lv = lrf[r * MAX_IN + k];
#pragma unroll
      for (int oi = 0; oi < 4; oi++) acc[oi] += lefts[oi * LOW_RANK + r] * lv;
    }
#pragma unroll
    for (int oi = 0; oi < 4; oi++)
      Wbf[(size_t)(o0 + oi) * MAX_IN + k] = f2bf(acc[oi]);
  }
}

// ---------------- kernel 2: GEMM, m97-regime  C = Xbf @ Wbf^T + bias ----------------
// 128x128 tile, BK=32, NT=32, 4 waves (2M x 2N), wave tile 64x64 (4x4 frags
// of 16x16x32). 2 LDS slots x 16 KB = 32 KB -> ~3 blocks/CU co-resident
// (inter-block overlap is the lever; R9/R10 proved 256^2 can't fit 2 blocks).
// Rotation (R10-verified logic): stage(t+1) -> vmcnt(4) -> barrier ->
// 8 ds_read_b128 + 16 MFMA -> barrier.
// Swizzle (R10-verified): row = 32 ushorts = 4 x 16B chunks; phys chunk =
// logical ^ ((r>>1)&3); staged via inverse-swizzled GLOBAL source + linear
// gload_lds dest (rule #21).
__global__ __launch_bounds__(256) void gemm_kernel(
    const unsigned short* __restrict__ A,   // [M][K] bf16
    const unsigned short* __restrict__ B,   // [N][K] bf16 (= W)
    const float* __restrict__ bias,         // [N]
    float* __restrict__ C) {                // [M][N] fp32
  constexpr int K = MAX_IN;
  constexpr int N = MAX_OUT;
  constexpr int SLOT = 8192;               // ushorts per slot (A 4096 + B 4096)
  constexpr int BOFF = 4096;
  constexpr int NT = K / 32;               // 32
  __shared__ __align__(16) unsigned short lds[2 * SLOT];  // 32 KB

  const int tid = threadIdx.x;             // 0..255
  const int lane = tid & 63;
  const int w = tid >> 6;                  // wave 0..3
  const int wm = w >> 1, wn = w & 1;       // 2M x 2N
  const int fl = lane & 15, hi = lane >> 4;

  // XCD macro-map: 2048 blocks, XCD gets a 16x16 macro-tile (A/B panels 8 MB)
  const int orig = blockIdx.x;
  const int xcd = orig & 7;
  const int mj = orig >> 3;                // 0..255
  const int bm = ((xcd >> 1) * 16 + (mj >> 4)) * 128;   // 64 M-tiles
  const int bn = ((xcd & 1) * 16 + (mj & 15)) * 128;    // 32 N-tiles

  // staging: thread covers rows rid, rid+64; phys chunk tid&3;
  // logical chunk cst = (tid&3) ^ ((rid>>1)&3)  (same for rid+64)
  const int rid = tid >> 2;
  const int cst = (tid & 3) ^ ((rid >> 1) & 3);
  const unsigned short* Asrc = A + (size_t)(bm + rid) * K + cst * 8;
  const unsigned short* Bsrc = B + (size_t)(bn + rid) * K + cst * 8;

  // fragment reads: row r, logical chunk hi -> phys chunk hi ^ ((r>>1)&3)
  int aoff[4], boff[4];
#pragma unroll
  for (int m = 0; m < 4; m++) {
    const int r = wm * 64 + m * 16 + fl;
    aoff[m] = r * 32 + ((hi ^ ((r >> 1) & 3)) * 8);
  }
#pragma unroll
  for (int n = 0; n < 4; n++) {
    const int r = wn * 64 + n * 16 + fl;
    boff[n] = BOFF + r * 32 + ((hi ^ ((r >> 1) & 3)) * 8);
  }

  f32x4 acc[4][4];
#pragma unroll
  for (int m = 0; m < 4; m++)
#pragma unroll
    for (int n = 0; n < 4; n++) acc[m][n] = (f32x4){0.f, 0.f, 0.f, 0.f};

#define STAGE(s, kt)                                                    \
  do {                                                                  \
    unsigned short* lb_ = &lds[(s) * SLOT];                             \
    gload16(Asrc + (kt) * 32, &lb_[tid * 8]);                           \
    gload16(Asrc + (size_t)64 * K + (kt) * 32, &lb_[(256 + tid) * 8]);  \
    gload16(Bsrc + (kt) * 32, &lb_[BOFF + tid * 8]);                    \
    gload16(Bsrc + (size_t)64 * K + (kt) * 32,                          \
            &lb_[BOFF + (256 + tid) * 8]);                              \
  } while (0)

  STAGE(0, 0);

  for (int t = 0; t < NT; ++t) {
    if (t + 1 < NT) {
      STAGE((t + 1) & 1, t + 1);
      asm volatile("s_waitcnt vmcnt(4)" ::: "memory");  // tile t landed
    } else {
      asm volatile("s_waitcnt vmcnt(0)" ::: "memory");
    }
    __builtin_amdgcn_s_barrier();
    __builtin_amdgcn_sched_barrier(0);

    const unsigned short* lb = &lds[(t & 1) * SLOT];
    short8 a[4], b[4];
#pragma unroll
    for (int m = 0; m < 4; m++) a[m] = *(const short8*)&lb[aoff[m]];
#pragma unroll
    for (int n = 0; n < 4; n++) b[n] = *(const short8*)&lb[boff[n]];
    __builtin_amdgcn_s_setprio(1);
#pragma unroll
    for (int m = 0; m < 4; m++)
#pragma unroll
      for (int n = 0; n < 4; n++)
        acc[m][n] = __builtin_amdgcn_mfma_f32_16x16x32_bf16(a[m], b[n], acc[m][n], 0, 0, 0);
    __builtin_amdgcn_s_setprio(0);
    __builtin_amdgcn_s_barrier();
    __builtin_amdgcn_sched_barrier(0);
  }
#undef STAGE

  // ---- epilogue: C/D layout col=lane&15, row=(lane>>4)*4+j ----
  float bv[4];
#pragma unroll
  for (int n = 0; n < 4; n++) bv[n] = bias[bn + wn * 64 + n * 16 + fl];
#pragma unroll
  for (int m = 0; m < 4; m++) {
    const int gr0 = bm + wm * 64 + m * 16 + hi * 4;
#pragma unroll
    for (int n = 0; n < 4; n++) {
      const int gc = bn + wn * 64 + n * 16 + fl;
#pragma unroll
      for (int jj = 0; jj < 4; jj++)
        C[(size_t)(gr0 + jj) * N + gc] = acc[m][n][jj] + bv[n];
    }
  }
}

// ---------------- launcher ----------------
extern "C" void kernel_launch(void* const* d_in, const int* in_sizes, int n_in,
                              void* d_out, int out_size, void* d_ws, size_t ws_size,
                              hipStream_t stream) {
  const float* x      = (const float*)d_in[0];
  const float* embed  = (const float*)d_in[1];
  const float* base_w = (const float*)d_in[2];
  const float* base_b = (const float*)d_in[3];
  const float* lrf    = (const float*)d_in[4];
  const float* w1     = (const float*)d_in[5];
  const float* b1     = (const float*)d_in[6];
  const float* w2     = (const float*)d_in[7];
  const float* b2     = (const float*)d_in[8];
  float* out = (float*)d_out;

  char* ws = (char*)d_ws;
  unsigned short* Xbf = (unsigned short*)ws;                                   // 16 MB
  unsigned short* Wbf = (unsigned short*)(ws + (size_t)BATCH_M * MAX_IN * 2);  // 8 MB

  // blocks 0..1023 build W; blocks 1024..3071 convert X
  hipLaunchKernelGGL(prep_kernel, dim3(1024 + 2048), dim3(256), 0, stream,
                     x, Xbf, w1, b1, embed, w2, b2, base_w, lrf, Wbf);
  hipLaunchKernelGGL(gemm_kernel, dim3((BATCH_M / 128) * (MAX_OUT / 128)), dim3(256), 0, stream,
                     Xbf, Wbf, base_b, out);
}